// Round 2
// baseline (947.272 us; speedup 1.0000x reference)
//
#include <hip/hip_runtime.h>

#define B_DIM 256
#define H_DIM 4608
#define N_TOT 18432          // 4*H
#define K_X   512
#define K_TOT 5120
#define KT    32
#define NSTEP (K_TOT / KT)   // 160
#define LDA   40             // padded LDS row stride (bf16 elems)
#define NJB   288            // j-tiles (18432/64 N per tile, 16 j x 4 gates)

typedef __attribute__((ext_vector_type(8))) short  short8;   // 8 x bf16 frag
typedef __attribute__((ext_vector_type(4))) float  floatx4;

static __device__ __forceinline__ unsigned pkbf(float a, float b){
  unsigned ua = (__float_as_uint(a) + 0x8000u) >> 16;
  unsigned ub = (__float_as_uint(b) + 0x8000u) & 0xFFFF0000u;
  return ua | ub;
}
static __device__ __forceinline__ float sigm(float v){
  return 1.0f / (1.0f + __expf(-v));
}
static __device__ __forceinline__ float tanh_fast(float v){
  float ax = fabsf(v);
  float e  = __expf(-2.0f * ax);
  float t  = (1.0f - e) / (1.0f + e);
  return copysignf(t, v);
}

// ---------------------------------------------------------------------------
// K-split gates GEMM: grid = NJB * KS blocks. Block (jb, kc) computes the
// partial 256x64 tile over K chunk [kc*K_TOT/KS, ...) and stores fp32
// partials to pbuf[kc][b][g*H+j]. W is read exactly once (chunks are
// disjoint W columns); x/h0 re-reads are L2/L3-served (5.2 MB total).
// ---------------------------------------------------------------------------
template<int KS>
__global__ __launch_bounds__(256, 5) void gates_gemm_partial(
    const float* __restrict__ x,   const float* __restrict__ h0,
    const float* __restrict__ Wih, const float* __restrict__ Whh,
    float* __restrict__ pbuf)
{
  constexpr int KC  = K_TOT / KS;   // K per chunk
  constexpr int NIT = KC / KT;      // iterations

  __shared__ __align__(16) unsigned short As[B_DIM * LDA];
  __shared__ __align__(16) unsigned short Bs[64 * LDA];

  const int t    = threadIdx.x;
  const int jb   = blockIdx.x % NJB;
  const int kc   = blockIdx.x / NJB;
  const int j0   = jb * 16;
  const int kbeg = kc * KC;
  const int w    = t >> 6;
  const int l    = t & 63;
  const int q    = l >> 4;
  const int col  = l & 15;
  const int jj   = j0 + col;

  const int arow = t >> 2;
  const int k8   = (t & 3) * 8;
  const int nloc = t >> 2;
  const int gate = nloc >> 4;
  const int jl   = nloc & 15;
  const long wrowg = (long)gate * H_DIM + j0 + jl;

  long offAx[4], offAh[4];
  #pragma unroll
  for (int rep = 0; rep < 4; ++rep){
    int row = rep * 64 + arow;
    offAx[rep] = (long)row * K_X   + k8;
    offAh[rep] = (long)row * H_DIM + k8;
  }
  const long offBx = wrowg * K_X   + k8;
  const long offBh = wrowg * H_DIM + k8;

  floatx4 acc[4][4];
  #pragma unroll
  for (int mt = 0; mt < 4; ++mt)
    #pragma unroll
    for (int nt = 0; nt < 4; ++nt)
      acc[mt][nt] = floatx4{0.f, 0.f, 0.f, 0.f};

  floatx4 pa[4][2];
  floatx4 pb[2];

  auto load_tile = [&](int ko){
    if (ko < K_X){
      #pragma unroll
      for (int rep = 0; rep < 4; ++rep){
        const float* p = x + offAx[rep] + ko;
        pa[rep][0] = *(const floatx4*)p;
        pa[rep][1] = *(const floatx4*)(p + 4);
      }
      const float* pB = Wih + offBx + ko;
      pb[0] = *(const floatx4*)pB;
      pb[1] = *(const floatx4*)(pB + 4);
    } else {
      const int kh = ko - K_X;
      #pragma unroll
      for (int rep = 0; rep < 4; ++rep){
        const float* p = h0 + offAh[rep] + kh;
        pa[rep][0] = *(const floatx4*)p;
        pa[rep][1] = *(const floatx4*)(p + 4);
      }
      const float* pB = Whh + offBh + kh;
      pb[0] = *(const floatx4*)pB;
      pb[1] = *(const floatx4*)(pB + 4);
    }
  };

  load_tile(kbeg);

  const int wrow = w * 64;
  const int aoff = (wrow + col) * LDA + q * 8;
  const int boff = col * LDA + q * 8;

  for (int kt = 0; kt < NIT; ++kt){
    __syncthreads();
    #pragma unroll
    for (int rep = 0; rep < 4; ++rep){
      uint4 wv;
      wv.x = pkbf(pa[rep][0].x, pa[rep][0].y);
      wv.y = pkbf(pa[rep][0].z, pa[rep][0].w);
      wv.z = pkbf(pa[rep][1].x, pa[rep][1].y);
      wv.w = pkbf(pa[rep][1].z, pa[rep][1].w);
      *(uint4*)&As[(rep * 64 + arow) * LDA + k8] = wv;
    }
    {
      uint4 wv;
      wv.x = pkbf(pb[0].x, pb[0].y);
      wv.y = pkbf(pb[0].z, pb[0].w);
      wv.z = pkbf(pb[1].x, pb[1].y);
      wv.w = pkbf(pb[1].z, pb[1].w);
      *(uint4*)&Bs[nloc * LDA + k8] = wv;
    }
    __syncthreads();

    if (kt + 1 < NIT) load_tile(kbeg + (kt + 1) * KT);

    short8 af[4], bf[4];
    #pragma unroll
    for (int mt = 0; mt < 4; ++mt)
      af[mt] = *(const short8*)&As[aoff + mt * 16 * LDA];
    #pragma unroll
    for (int nt = 0; nt < 4; ++nt)
      bf[nt] = *(const short8*)&Bs[boff + nt * 16 * LDA];
    #pragma unroll
    for (int mt = 0; mt < 4; ++mt)
      #pragma unroll
      for (int nt = 0; nt < 4; ++nt)
        acc[mt][nt] = __builtin_amdgcn_mfma_f32_16x16x32_bf16(af[mt], bf[nt], acc[mt][nt], 0, 0, 0);
  }

  // store fp32 partials
  float* base = pbuf + (size_t)kc * ((size_t)B_DIM * N_TOT);
  #pragma unroll
  for (int mt = 0; mt < 4; ++mt){
    #pragma unroll
    for (int r = 0; r < 4; ++r){
      int brow = wrow + mt * 16 + q * 4 + r;
      float* rp = base + (size_t)brow * N_TOT + jj;
      #pragma unroll
      for (int nt = 0; nt < 4; ++nt)
        rp[nt * H_DIM] = acc[mt][nt][r];
    }
  }
}

// ---------------------------------------------------------------------------
// Epilogue: sum KS partials + biases, LSTM cell, write h_new/c_new.
// 512 blocks x 256 thr: block = (b, half-row); 9 j-iters of 256.
// ---------------------------------------------------------------------------
__global__ __launch_bounds__(256) void lstm_epilogue(
    const float* __restrict__ pbuf, int KS,
    const float* __restrict__ c0,
    const float* __restrict__ bih, const float* __restrict__ bhh,
    float* __restrict__ outH, float* __restrict__ outC)
{
  const int b    = blockIdx.x >> 1;
  const int half = blockIdx.x & 1;
  const int t    = threadIdx.x;
  const size_t CH = (size_t)B_DIM * N_TOT;

  for (int it = 0; it < 9; ++it){
    int j = half * 2304 + it * 256 + t;
    float g4[4];
    #pragma unroll
    for (int g = 0; g < 4; ++g)
      g4[g] = bih[g * H_DIM + j] + bhh[g * H_DIM + j];
    for (int kc = 0; kc < KS; ++kc){
      const float* pp = pbuf + (size_t)kc * CH + (size_t)b * N_TOT + j;
      #pragma unroll
      for (int g = 0; g < 4; ++g)
        g4[g] += pp[g * H_DIM];
    }
    float cp = c0[(size_t)b * H_DIM + j];
    float cn = sigm(g4[1]) * cp + sigm(g4[0]) * tanh_fast(g4[2]);
    float hn = sigm(g4[3]) * tanh_fast(cn);
    outH[(size_t)b * H_DIM + j] = hn;
    outC[(size_t)b * H_DIM + j] = cn;
  }
}

// ---------------------------------------------------------------------------
// Round-1 fused kernel kept as fallback if ws is too small for K-split.
// ---------------------------------------------------------------------------
__global__ __launch_bounds__(256, 2) void lstm_gates_fused(
    const float* __restrict__ x,   const float* __restrict__ h0,
    const float* __restrict__ c0,
    const float* __restrict__ Wih, const float* __restrict__ Whh,
    const float* __restrict__ bih, const float* __restrict__ bhh,
    float* __restrict__ outH, float* __restrict__ outC)
{
  __shared__ __align__(16) unsigned short As[B_DIM * LDA];
  __shared__ __align__(16) unsigned short Bs[64 * LDA];

  const int t   = threadIdx.x;
  const int j0  = blockIdx.x * 16;
  const int w   = t >> 6;
  const int l   = t & 63;
  const int q   = l >> 4;
  const int col = l & 15;
  const int jj  = j0 + col;

  const int arow = t >> 2;
  const int k8   = (t & 3) * 8;
  const int nloc = t >> 2;
  const int gate = nloc >> 4;
  const int jl   = nloc & 15;
  const long wrowg = (long)gate * H_DIM + j0 + jl;

  long offAx[4], offAh[4];
  #pragma unroll
  for (int rep = 0; rep < 4; ++rep){
    int row = rep * 64 + arow;
    offAx[rep] = (long)row * K_X   + k8;
    offAh[rep] = (long)row * H_DIM + k8;
  }
  const long offBx = wrowg * K_X   + k8;
  const long offBh = wrowg * H_DIM + k8;

  floatx4 acc[4][4];
  #pragma unroll
  for (int nt = 0; nt < 4; ++nt){
    float bsum = bih[nt * H_DIM + jj] + bhh[nt * H_DIM + jj];
    floatx4 v = {bsum, bsum, bsum, bsum};
    #pragma unroll
    for (int mt = 0; mt < 4; ++mt) acc[mt][nt] = v;
  }

  floatx4 pa[4][2];
  floatx4 pb[2];

  auto load_tile = [&](int ko){
    if (ko < K_X){
      #pragma unroll
      for (int rep = 0; rep < 4; ++rep){
        const float* p = x + offAx[rep] + ko;
        pa[rep][0] = *(const floatx4*)p;
        pa[rep][1] = *(const floatx4*)(p + 4);
      }
      const float* pB = Wih + offBx + ko;
      pb[0] = *(const floatx4*)pB;
      pb[1] = *(const floatx4*)(pB + 4);
    } else {
      const int kh = ko - K_X;
      #pragma unroll
      for (int rep = 0; rep < 4; ++rep){
        const float* p = h0 + offAh[rep] + kh;
        pa[rep][0] = *(const floatx4*)p;
        pa[rep][1] = *(const floatx4*)(p + 4);
      }
      const float* pB = Whh + offBh + kh;
      pb[0] = *(const floatx4*)pB;
      pb[1] = *(const floatx4*)(pB + 4);
    }
  };

  load_tile(0);

  const int wrow = w * 64;
  const int aoff = (wrow + col) * LDA + q * 8;
  const int boff = col * LDA + q * 8;

  for (int kt = 0; kt < NSTEP; ++kt){
    __syncthreads();
    #pragma unroll
    for (int rep = 0; rep < 4; ++rep){
      uint4 wv;
      wv.x = pkbf(pa[rep][0].x, pa[rep][0].y);
      wv.y = pkbf(pa[rep][0].z, pa[rep][0].w);
      wv.z = pkbf(pa[rep][1].x, pa[rep][1].y);
      wv.w = pkbf(pa[rep][1].z, pa[rep][1].w);
      *(uint4*)&As[(rep * 64 + arow) * LDA + k8] = wv;
    }
    {
      uint4 wv;
      wv.x = pkbf(pb[0].x, pb[0].y);
      wv.y = pkbf(pb[0].z, pb[0].w);
      wv.z = pkbf(pb[1].x, pb[1].y);
      wv.w = pkbf(pb[1].z, pb[1].w);
      *(uint4*)&Bs[nloc * LDA + k8] = wv;
    }
    __syncthreads();

    if (kt + 1 < NSTEP) load_tile((kt + 1) * KT);

    short8 af[4], bf[4];
    #pragma unroll
    for (int mt = 0; mt < 4; ++mt)
      af[mt] = *(const short8*)&As[aoff + mt * 16 * LDA];
    #pragma unroll
    for (int nt = 0; nt < 4; ++nt)
      bf[nt] = *(const short8*)&Bs[boff + nt * 16 * LDA];
    #pragma unroll
    for (int mt = 0; mt < 4; ++mt)
      #pragma unroll
      for (int nt = 0; nt < 4; ++nt)
        acc[mt][nt] = __builtin_amdgcn_mfma_f32_16x16x32_bf16(af[mt], bf[nt], acc[mt][nt], 0, 0, 0);
  }

  #pragma unroll
  for (int mt = 0; mt < 4; ++mt){
    #pragma unroll
    for (int r = 0; r < 4; ++r){
      int brow = wrow + mt * 16 + q * 4 + r;
      float iv = acc[mt][0][r];
      float fv = acc[mt][1][r];
      float gv = acc[mt][2][r];
      float ov = acc[mt][3][r];
      float cp = c0[(long)brow * H_DIM + jj];
      float cn = sigm(fv) * cp + sigm(iv) * tanh_fast(gv);
      float hn = sigm(ov) * tanh_fast(cn);
      outH[(long)brow * H_DIM + jj] = hn;
      outC[(long)brow * H_DIM + jj] = cn;
    }
  }
}

// ---------------------------------------------------------------------------
// y kernel v2: grid (256 b, 4 o-chunks) = 1024 blocks -> 4 blocks/CU.
// ---------------------------------------------------------------------------
__global__ __launch_bounds__(256) void y_kernel(
    const float* __restrict__ x, const float* __restrict__ hnew,
    const float* __restrict__ W0, const float* __restrict__ b0,
    float* __restrict__ y)
{
  __shared__ float xs[512];
  __shared__ float zs[4];
  const int b  = blockIdx.x;
  const int oc = blockIdx.y;
  const int t  = threadIdx.x;
  const int w  = t >> 6;
  const int l  = t & 63;

  const float* xrow = x + (long)b * 512;
  xs[t]       = xrow[t];
  xs[t + 256] = xrow[t + 256];
  __syncthreads();

  const float* hrow = hnew + (long)b * H_DIM;

  // z[w] = dot(dw2[b,w,:], x[b,:])
  {
    const float* d2 = hrow + 2048 + w * 512;
    float p = 0.f;
    #pragma unroll
    for (int j = 0; j < 8; ++j)
      p += d2[l + 64 * j] * xs[l + 64 * j];
    #pragma unroll
    for (int off = 32; off > 0; off >>= 1)
      p += __shfl_down(p, off);
    if (l == 0) zs[w] = p;
  }
  __syncthreads();
  const float z0 = zs[0], z1 = zs[1], z2 = zs[2], z3 = zs[3];

  // each wave: 32 outputs in this o-chunk
  #pragma unroll 4
  for (int oo = 0; oo < 32; ++oo){
    int o = oc * 128 + w * 32 + oo;
    const float* wr = W0 + (long)o * 512;
    float p = 0.f;
    #pragma unroll
    for (int j = 0; j < 8; ++j)
      p += wr[l + 64 * j] * xs[l + 64 * j];
    #pragma unroll
    for (int off = 32; off > 0; off >>= 1)
      p += __shfl_down(p, off);
    if (l == 0){
      float4 d1 = *(const float4*)&hrow[o * 4];
      float r = p + b0[o] + hrow[4096 + o]
              + d1.x * z0 + d1.y * z1 + d1.z * z2 + d1.w * z3;
      y[(long)b * 512 + o] = r;
    }
  }
}

extern "C" void kernel_launch(void* const* d_in, const int* in_sizes, int n_in,
                              void* d_out, int out_size, void* d_ws, size_t ws_size,
                              hipStream_t stream)
{
  const float* x   = (const float*)d_in[0];
  const float* h0  = (const float*)d_in[1];
  const float* c0  = (const float*)d_in[2];
  const float* Wih = (const float*)d_in[3];
  const float* Whh = (const float*)d_in[4];
  const float* bih = (const float*)d_in[5];
  const float* bhh = (const float*)d_in[6];
  const float* W0  = (const float*)d_in[7];
  const float* b0  = (const float*)d_in[8];

  float* out  = (float*)d_out;
  float* y    = out;
  float* outH = out + 131072;
  float* outC = out + 131072 + 1179648;

  const size_t chunk = (size_t)B_DIM * N_TOT * sizeof(float); // 18.9 MB
  float* pbuf = (float*)d_ws;

  if (ws_size >= 4 * chunk){
    hipLaunchKernelGGL((gates_gemm_partial<4>), dim3(NJB * 4), dim3(256), 0, stream,
                       x, h0, Wih, Whh, pbuf);
    hipLaunchKernelGGL(lstm_epilogue, dim3(512), dim3(256), 0, stream,
                       pbuf, 4, c0, bih, bhh, outH, outC);
  } else if (ws_size >= 2 * chunk){
    hipLaunchKernelGGL((gates_gemm_partial<2>), dim3(NJB * 2), dim3(256), 0, stream,
                       x, h0, Wih, Whh, pbuf);
    hipLaunchKernelGGL(lstm_epilogue, dim3(512), dim3(256), 0, stream,
                       pbuf, 2, c0, bih, bhh, outH, outC);
  } else {
    hipLaunchKernelGGL(lstm_gates_fused, dim3(NJB), dim3(256), 0, stream,
                       x, h0, c0, Wih, Whh, bih, bhh, outH, outC);
  }

  hipLaunchKernelGGL(y_kernel, dim3(256, 4), dim3(256), 0, stream,
                     x, outH, W0, b0, y);
}

// Round 3
// 876.862 us; speedup vs baseline: 1.0803x; 1.0803x over previous
//
#include <hip/hip_runtime.h>

#define B_DIM 256
#define H_DIM 4608
#define N_TOT 18432
#define K_X   512
#define K_TOT 5120          // 512 (x) + 4608 (h0)
#define KT    32
#define NSTEP (K_TOT / KT)  // 160
#define NJB   288           // N tiles: 18432 / 64  (64 = 4 gates x 16 j)

typedef __attribute__((ext_vector_type(8))) short    short8;   // bf16x8 MFMA A/B frag
typedef __attribute__((ext_vector_type(4))) float    floatx4;  // MFMA C/D frag
typedef __attribute__((ext_vector_type(4))) unsigned uintx4;

static __device__ __forceinline__ unsigned pkbf(float a, float b){
  unsigned ua = (__float_as_uint(a) + 0x8000u) >> 16;
  unsigned ub = (__float_as_uint(b) + 0x8000u) & 0xFFFF0000u;
  return ua | ub;
}
static __device__ __forceinline__ unsigned short bf1(float v){
  return (unsigned short)((__float_as_uint(v) + 0x8000u) >> 16);
}
static __device__ __forceinline__ float sigm(float v){
  return 1.0f / (1.0f + __expf(-v));
}
static __device__ __forceinline__ float tanh_fast(float v){
  float ax = fabsf(v);
  float e  = __expf(-2.0f * ax);
  float t  = (1.0f - e) / (1.0f + e);
  return copysignf(t, v);
}

// ---------------------------------------------------------------------------
// Prep: (1) A = [x | h0] as bf16 [256][5120] (fits per-XCD 4MB L2 -> all
// GEMM A-rereads are L2 hits, zero in-loop conversion, loads land directly
// in MFMA fragment order). (2) W0T[i][o] = W0[o][i] fp32, for coalesced
// lane-per-output y kernel.
// ---------------------------------------------------------------------------
__global__ __launch_bounds__(256) void prep_kernel(
    const float* __restrict__ x, const float* __restrict__ h0,
    const float* __restrict__ W0,
    unsigned short* __restrict__ Aws, float* __restrict__ W0T)
{
  const int blk = blockIdx.x;
  const int t   = threadIdx.x;
  if (blk < 256){
    const float* xr = x  + (size_t)blk * K_X;
    const float* hr = h0 + (size_t)blk * H_DIM;
    unsigned short* ar = Aws + (size_t)blk * K_TOT;
    #pragma unroll
    for (int i = 0; i < 20; ++i){
      int c = i * 256 + t;
      float v = (c < K_X) ? xr[c] : hr[c - K_X];
      ar[c] = bf1(v);
    }
  } else {
    int b2 = blk - 256;                 // 0..63
    #pragma unroll
    for (int i = 0; i < 16; ++i){
      int idx  = b2 * 4096 + i * 256 + t;   // 0..262143
      int irow = idx >> 9;                  // input dim
      int o    = idx & 511;                 // output dim
      W0T[idx] = W0[o * 512 + irow];
    }
  }
}

// ---------------------------------------------------------------------------
// LDS-free fused gates GEMM + LSTM cell. Grid 288 x 256thr (4 waves).
// Tile: M=256 (full batch, weights read exactly once) x N=64 (4 gates x 16 j).
// Wave w owns rows [64w,64w+64). Per K-step(32): A-frags = 4 x 16B bf16
// direct loads (L2-resident Aws); B = 8 x float4 fp32 weight loads (all 4
// waves hit same lines -> L1), converted to bf16 in regs. acc[mt][gate] ->
// i,f,g,o for one (b,j) share lane+reg -> zero-movement LSTM epilogue.
// No barriers: waves stream independently; 2-deep ping-pong prefetch.
// ---------------------------------------------------------------------------
__global__ __launch_bounds__(256) void gates_kernel(
    const unsigned short* __restrict__ A,
    const float* __restrict__ Wih, const float* __restrict__ Whh,
    const float* __restrict__ bih, const float* __restrict__ bhh,
    const float* __restrict__ c0,
    float* __restrict__ outH, float* __restrict__ outC)
{
  const int t    = threadIdx.x;
  const int w    = t >> 6;
  const int l    = t & 63;
  const int q    = l >> 4;
  const int col  = l & 15;
  const int j0   = blockIdx.x * 16;
  const int jj   = j0 + col;
  const int wrow = w * 64;

  // per-lane base pointers
  const unsigned short* pA[4];
  #pragma unroll
  for (int mt = 0; mt < 4; ++mt)
    pA[mt] = A + (size_t)(wrow + mt * 16 + col) * K_TOT + q * 8;

  const float* pBi[4];  // Wih rows (row length 512)
  const float* pBh[4];  // Whh rows (row length 4608)
  #pragma unroll
  for (int nt = 0; nt < 4; ++nt){
    size_t r = (size_t)nt * H_DIM + jj;
    pBi[nt] = Wih + r * K_X   + q * 8;
    pBh[nt] = Whh + r * H_DIM + q * 8;
  }

  floatx4 acc[4][4];
  #pragma unroll
  for (int nt = 0; nt < 4; ++nt){
    float bsum = bih[nt * H_DIM + jj] + bhh[nt * H_DIM + jj];
    floatx4 v = {bsum, bsum, bsum, bsum};
    #pragma unroll
    for (int mt = 0; mt < 4; ++mt) acc[mt][nt] = v;
  }

  short8  aq[2][4];
  floatx4 bq[2][8];

  auto lda = [&](int u, int ko){
    #pragma unroll
    for (int mt = 0; mt < 4; ++mt)
      aq[u][mt] = *(const short8*)(pA[mt] + ko);
  };
  auto ldb = [&](int u, int ko){
    if (ko < K_X){
      #pragma unroll
      for (int nt = 0; nt < 4; ++nt){
        const float* p = pBi[nt] + ko;
        bq[u][nt * 2]     = *(const floatx4*)p;
        bq[u][nt * 2 + 1] = *(const floatx4*)(p + 4);
      }
    } else {
      int kh = ko - K_X;
      #pragma unroll
      for (int nt = 0; nt < 4; ++nt){
        const float* p = pBh[nt] + kh;
        bq[u][nt * 2]     = *(const floatx4*)p;
        bq[u][nt * 2 + 1] = *(const floatx4*)(p + 4);
      }
    }
  };
  auto comp = [&](int u){
    #pragma unroll
    for (int nt = 0; nt < 4; ++nt){
      floatx4 c0v = bq[u][nt * 2], c1v = bq[u][nt * 2 + 1];
      uintx4 cv = { pkbf(c0v.x, c0v.y), pkbf(c0v.z, c0v.w),
                    pkbf(c1v.x, c1v.y), pkbf(c1v.z, c1v.w) };
      short8 bf = __builtin_bit_cast(short8, cv);
      #pragma unroll
      for (int mt = 0; mt < 4; ++mt)
        acc[mt][nt] = __builtin_amdgcn_mfma_f32_16x16x32_bf16(aq[u][mt], bf, acc[mt][nt], 0, 0, 0);
    }
  };

  lda(0, 0); ldb(0, 0);
  for (int kt = 0; kt < NSTEP; kt += 2){
    int ko1 = (kt + 1) * KT;
    int ko2 = (kt + 2) * KT;
    if (ko1 < K_TOT){ lda(1, ko1); ldb(1, ko1); }
    comp(0);
    if (ko2 < K_TOT){ lda(0, ko2); ldb(0, ko2); }
    comp(1);
  }

  // fused LSTM epilogue: D row = q*4 + r, col = lane&15
  #pragma unroll
  for (int mt = 0; mt < 4; ++mt){
    #pragma unroll
    for (int r = 0; r < 4; ++r){
      int brow = wrow + mt * 16 + q * 4 + r;
      float iv = acc[mt][0][r];
      float fv = acc[mt][1][r];
      float gv = acc[mt][2][r];
      float ov = acc[mt][3][r];
      float cp = c0[(size_t)brow * H_DIM + jj];
      float cn = sigm(fv) * cp + sigm(iv) * tanh_fast(gv);
      float hn = sigm(ov) * tanh_fast(cn);
      outH[(size_t)brow * H_DIM + jj] = hn;
      outC[(size_t)brow * H_DIM + jj] = cn;
    }
  }
}

// ---------------------------------------------------------------------------
// y kernel v3: grid 512 = (b, half), lane-per-output over pre-transposed W0T.
// No per-output shuffle chains; 4 split accumulators break the FMA chain.
// ---------------------------------------------------------------------------
__global__ __launch_bounds__(256) void y_kernel(
    const float* __restrict__ x, const float* __restrict__ hnew,
    const float* __restrict__ W0T, const float* __restrict__ b0,
    float* __restrict__ y)
{
  __shared__ float xs[512];
  __shared__ float zs[4];
  const int blk  = blockIdx.x;
  const int b    = blk >> 1;
  const int half = blk & 1;
  const int t    = threadIdx.x;
  const int w    = t >> 6;
  const int l    = t & 63;

  const float* xrow = x + (size_t)b * 512;
  xs[t]       = xrow[t];
  xs[t + 256] = xrow[t + 256];
  __syncthreads();

  const float* hrow = hnew + (size_t)b * H_DIM;

  // z[r] = dot(dw2[b,r,:], x[b,:]);  dw2[b,r,i] = h_new[b, 2048 + r*512 + i]
  {
    const float* d2 = hrow + 2048 + w * 512;
    float p = 0.f;
    #pragma unroll
    for (int j = 0; j < 8; ++j)
      p += d2[l + 64 * j] * xs[l + 64 * j];
    #pragma unroll
    for (int off = 32; off > 0; off >>= 1)
      p += __shfl_down(p, off);
    if (l == 0) zs[w] = p;
  }
  __syncthreads();

  const int o = half * 256 + t;
  float p0 = 0.f, p1 = 0.f, p2 = 0.f, p3 = 0.f;
  for (int k = 0; k < 512; k += 4){
    p0 += W0T[(size_t)(k + 0) * 512 + o] * xs[k + 0];
    p1 += W0T[(size_t)(k + 1) * 512 + o] * xs[k + 1];
    p2 += W0T[(size_t)(k + 2) * 512 + o] * xs[k + 2];
    p3 += W0T[(size_t)(k + 3) * 512 + o] * xs[k + 3];
  }
  float pt = (p0 + p1) + (p2 + p3);
  float4 d1 = *(const float4*)&hrow[o * 4];     // dw1[b,o,0..3]
  y[(size_t)b * 512 + o] = pt + b0[o] + hrow[4096 + o]
      + d1.x * zs[0] + d1.y * zs[1] + d1.z * zs[2] + d1.w * zs[3];
}

extern "C" void kernel_launch(void* const* d_in, const int* in_sizes, int n_in,
                              void* d_out, int out_size, void* d_ws, size_t ws_size,
                              hipStream_t stream)
{
  const float* x   = (const float*)d_in[0];
  const float* h0  = (const float*)d_in[1];
  const float* c0  = (const float*)d_in[2];
  const float* Wih = (const float*)d_in[3];
  const float* Whh = (const float*)d_in[4];
  const float* bih = (const float*)d_in[5];
  const float* bhh = (const float*)d_in[6];
  const float* W0  = (const float*)d_in[7];
  const float* b0  = (const float*)d_in[8];

  float* out  = (float*)d_out;
  float* y    = out;
  float* outH = out + 131072;               // 256*512
  float* outC = out + 131072 + 1179648;     // + 256*4608

  unsigned short* Aws = (unsigned short*)d_ws;                   // 2.62 MB
  float* W0T = (float*)((char*)d_ws + (size_t)B_DIM * K_TOT * 2); // 1 MB

  hipLaunchKernelGGL(prep_kernel, dim3(320), dim3(256), 0, stream,
                     x, h0, W0, Aws, W0T);
  hipLaunchKernelGGL(gates_kernel, dim3(NJB), dim3(256), 0, stream,
                     Aws, Wih, Whh, bih, bhh, c0, outH, outC);
  hipLaunchKernelGGL(y_kernel, dim3(512), dim3(256), 0, stream,
                     x, outH, W0T, b0, y);
}